// Round 13
// baseline (142.031 us; speedup 1.0000x reference)
//
#include <hip/hip_runtime.h>
#include <math.h>

// B=64, T=512, D=64, K=12, P=100
// R12 post-mortem: 2-t tiling (BS=256) regressed nll 58.9->93us: halved the
// wave pool of an SMEM-latency-bound kernel (occupancy 45->27%, VALUBusy
// 36->22%). Fusion itself was the win (total 159->131). This round: R10's
// proven 1-t BS=512 nll body + R12's fused 2-kernel structure + k-major map.

#define DD 64
#define BS 512  // one thread per t; T == 512

__device__ __forceinline__ float waveReduceSum(float v) {
#pragma unroll
  for (int off = 32; off > 0; off >>= 1) v += __shfl_down(v, off, 64);
  return v;
}
__device__ __forceinline__ double waveReduceSumD(double v) {
#pragma unroll
  for (int off = 32; off > 0; off >>= 1) v += __shfl_down(v, off, 64);
  return v;
}

// ws layout (floats): [0..768) nll_part  [768..768+P) regL_part
//                     [896..896+P) regM_part   (all plain stores, no init)
#define REGL_OFF 768
#define REGM_OFF 896

// ---- 1-t register-resident substitution, L via wave-uniform scalar loads ---
#define LQ4(I, Q) (*(const float4*)(Lg + (I) * DD + 4 * (Q)))

#define FMAQ(Q, I)                      \
  {                                     \
    float4 Lq = LQ4(I, Q);              \
    acc -= Lq.x * v##Q.x;               \
    acc -= Lq.y * v##Q.y;               \
    acc -= Lq.z * v##Q.z;               \
    acc -= Lq.w * v##Q.w;               \
  }

#define DOT0(I)
#define DOT1(I) DOT0(I) FMAQ(0, I)
#define DOT2(I) DOT1(I) FMAQ(1, I)
#define DOT3(I) DOT2(I) FMAQ(2, I)
#define DOT4(I) DOT3(I) FMAQ(3, I)
#define DOT5(I) DOT4(I) FMAQ(4, I)
#define DOT6(I) DOT5(I) FMAQ(5, I)
#define DOT7(I) DOT6(I) FMAQ(6, I)
#define DOT8(I) DOT7(I) FMAQ(7, I)
#define DOT9(I) DOT8(I) FMAQ(8, I)
#define DOT10(I) DOT9(I) FMAQ(9, I)
#define DOT11(I) DOT10(I) FMAQ(10, I)
#define DOT12(I) DOT11(I) FMAQ(11, I)
#define DOT13(I) DOT12(I) FMAQ(12, I)
#define DOT14(I) DOT13(I) FMAQ(13, I)
#define DOT15(I) DOT14(I) FMAQ(14, I)

#define ROWX(A)                                   \
  {                                               \
    float acc = v##A.x;                           \
    DOT##A(4 * A)                                 \
    float val = acc * rq.x;                       \
    v##A.x = val;                                 \
    maha += val * val;                            \
  }
#define ROWY(A)                                   \
  {                                               \
    float acc = v##A.y;                           \
    DOT##A(4 * A + 1)                             \
    float4 tq = LQ4(4 * A + 1, A);                \
    acc -= tq.x * v##A.x;                         \
    float val = acc * rq.y;                       \
    v##A.y = val;                                 \
    maha += val * val;                            \
  }
#define ROWZ(A)                                   \
  {                                               \
    float acc = v##A.z;                           \
    DOT##A(4 * A + 2)                             \
    float4 tq = LQ4(4 * A + 2, A);                \
    acc -= tq.x * v##A.x;                         \
    acc -= tq.y * v##A.y;                         \
    float val = acc * rq.z;                       \
    v##A.z = val;                                 \
    maha += val * val;                            \
  }
#define ROWW(A)                                   \
  {                                               \
    float acc = v##A.w;                           \
    DOT##A(4 * A + 3)                             \
    float4 tq = LQ4(4 * A + 3, A);                \
    acc -= tq.x * v##A.x;                         \
    acc -= tq.y * v##A.y;                         \
    acc -= tq.z * v##A.z;                         \
    float val = acc * rq.w;                       \
    v##A.w = val;                                 \
    maha += val * val;                            \
  }
#define QUAD(A)                                   \
  {                                               \
    float4 rq = *(const float4*)&rinv_s[4 * A];   \
    ROWX(A) ROWY(A) ROWZ(A) ROWW(A)               \
  }

#define LOADQ(Q)                                  \
  {                                               \
    float4 a = xr[Q];                             \
    float4 m = *(const float4*)(mug + 4 * (Q));   \
    v##Q.x = a.x - m.x;                           \
    v##Q.y = a.y - m.y;                           \
    v##Q.z = a.z - m.z;                           \
    v##Q.w = a.w - m.w;                           \
  }

__global__ __launch_bounds__(BS) void main_kernel(
    const float* __restrict__ x, const float* __restrict__ mu_pop,
    const float* __restrict__ L_pop, const float* __restrict__ mu_subj,
    const float* __restrict__ L_subj, const float* __restrict__ gamma,
    const int* __restrict__ sid, float* __restrict__ part,
    int B, int T, int K, int P) {
  __shared__ float rinv_s[DD];
  __shared__ float redA[BS / 64], redB[BS / 64];
  __shared__ float logdet_s;
  __shared__ int present_s;

  const int bx = blockIdx.x;
  const int tid = threadIdx.x;
  const int lane = tid & 63, wid = tid >> 6;
  const int NB = B * K;  // 768

  if (bx < NB) {
    // ---- NLL block: k-major map (same-b blocks share XCD; B % 8 == 0) ----
    const int b = bx % B;
    const int k = bx / B;
    const int s = __builtin_amdgcn_readfirstlane(sid[b]);
    const float* Lg  = L_subj  + ((size_t)s * K + k) * (DD * DD);
    const float* mug = mu_subj + ((size_t)s * K + k) * DD;

    if (tid < DD) {  // wave 0: rinv + logdet from the diagonal
      float d = Lg[tid * DD + tid];
      rinv_s[tid] = 1.0f / d;
      float lg = logf(d);
      lg = waveReduceSum(lg);
      if (tid == 0) logdet_s = lg;
    }
    __syncthreads();

    const float C0 = 58.81206612509905f;  // 0.5 * 64 * log(2*pi)
    const float logdet = logdet_s;

    const int t = tid;  // T == BS
    const float g = gamma[((size_t)b * T + t) * K + k];

    const float4* xr = (const float4*)(x + ((size_t)b * T + t) * DD);
    float4 v0, v1, v2, v3, v4, v5, v6, v7, v8, v9, v10, v11, v12, v13, v14, v15;
    LOADQ(0) LOADQ(1) LOADQ(2) LOADQ(3) LOADQ(4) LOADQ(5) LOADQ(6) LOADQ(7)
    LOADQ(8) LOADQ(9) LOADQ(10) LOADQ(11) LOADQ(12) LOADQ(13) LOADQ(14) LOADQ(15)

    float maha = 0.f;
    QUAD(0) QUAD(1) QUAD(2) QUAD(3) QUAD(4) QUAD(5) QUAD(6) QUAD(7)
    QUAD(8) QUAD(9) QUAD(10) QUAD(11) QUAD(12) QUAD(13) QUAD(14) QUAD(15)

    float acc = g * (0.5f * maha + logdet + C0);
    float wsum = waveReduceSum(acc);
    if (lane == 0) redA[wid] = wsum;
    __syncthreads();
    if (tid == 0) {
      float ssum = 0.f;
#pragma unroll
      for (int i = 0; i < BS / 64; ++i) ssum += redA[i];
      part[bx] = ssum;
    }
  } else {
    // ---- regularizer block: one subject p ----
    const int p = bx - NB;
    if (tid < 64) {  // wave 0: presence check
      int pr = (tid < B) ? (sid[tid] == p) : 0;
      unsigned long long m = __ballot(pr);
      if (tid == 0) present_s = (m != 0ULL);
    }
    __syncthreads();

    float accL = 0.f, accM = 0.f;
    if (present_s) {
      const int KDD4 = K * DD * DD / 4;  // 12288
      const float4* As = (const float4*)(L_subj + (size_t)p * K * DD * DD);
      const float4* Ap = (const float4*)L_pop;
      for (int i = tid; i < KDD4; i += BS) {
        float4 a = As[i], c = Ap[i];
        float dx = a.x - c.x, dy = a.y - c.y, dz = a.z - c.z, dw = a.w - c.w;
        accL += dx * dx + dy * dy + dz * dz + dw * dw;
      }
      const int KD4 = K * DD / 4;  // 192
      const float4* Ms = (const float4*)(mu_subj + (size_t)p * K * DD);
      const float4* Mp = (const float4*)mu_pop;
      for (int i = tid; i < KD4; i += BS) {
        float4 a = Ms[i], c = Mp[i];
        float dx = a.x - c.x, dy = a.y - c.y, dz = a.z - c.z, dw = a.w - c.w;
        accM += dx * dx + dy * dy + dz * dz + dw * dw;
      }
    }
    float l = waveReduceSum(accL), m2 = waveReduceSum(accM);
    if (lane == 0) { redA[wid] = l; redB[wid] = m2; }
    __syncthreads();
    if (tid == 0) {
      float sl = 0.f, sm = 0.f;
#pragma unroll
      for (int i = 0; i < BS / 64; ++i) { sl += redA[i]; sm += redB[i]; }
      part[REGL_OFF + p] = sl;
      part[REGM_OFF + p] = sm;
    }
  }
}

__global__ __launch_bounds__(256) void finalize_kernel(
    const float* __restrict__ part, const int* __restrict__ sid,
    const int* __restrict__ n_subj, float* __restrict__ out,
    int B, int K, int P, float n) {
  const int NB = B * K;
  const int tid = threadIdx.x;
  const int lane = tid & 63, wid = tid >> 6;
  __shared__ double rd[4][4];
  __shared__ int pres[128];

  double dn = 0.0, dl = 0.0, dm = 0.0, ds = 0.0;
  for (int i = tid; i < NB; i += 256) dn += (double)part[i];
  if (tid < P) {
    dl = (double)part[REGL_OFF + tid];
    dm = (double)part[REGM_OFF + tid];
  }
  if (tid < 128) pres[tid] = 0;
  __syncthreads();
  if (tid < B) pres[sid[tid]] = 1;
  __syncthreads();
  if (tid < P) ds = (double)pres[tid];

  dn = waveReduceSumD(dn); dl = waveReduceSumD(dl);
  dm = waveReduceSumD(dm); ds = waveReduceSumD(ds);
  if (lane == 0) { rd[0][wid] = dn; rd[1][wid] = dl; rd[2][wid] = dm; rd[3][wid] = ds; }
  __syncthreads();
  if (tid == 0) {
    double tn = rd[0][0] + rd[0][1] + rd[0][2] + rd[0][3];
    double tl = rd[1][0] + rd[1][1] + rd[1][2] + rd[1][3];
    double tm = rd[2][0] + rd[2][1] + rd[2][2] + rd[2][3];
    double ts = rd[3][0] + rd[3][1] + rd[3][2] + rd[3][3];
    double nll = tn / (double)n;
    double reg = (ts / (double)(*n_subj)) * (0.05 * tm + 0.05 * tl);
    out[0] = (float)(nll + reg);
  }
}

extern "C" void kernel_launch(void* const* d_in, const int* in_sizes, int n_in,
                              void* d_out, int out_size, void* d_ws, size_t ws_size,
                              hipStream_t stream) {
  const float* x       = (const float*)d_in[0];
  const float* mu_pop  = (const float*)d_in[1];
  const float* L_pop   = (const float*)d_in[2];
  const float* mu_subj = (const float*)d_in[3];
  const float* L_subj  = (const float*)d_in[4];
  const float* gamma   = (const float*)d_in[5];
  const int*   sid     = (const int*)d_in[6];
  const int*   nsub    = (const int*)d_in[7];

  const int B = in_sizes[6];             // 64
  const int K = in_sizes[1] / DD;        // 12
  const int T = in_sizes[0] / (B * DD);  // 512
  const int P = in_sizes[3] / (K * DD);  // 100

  float* part = (float*)d_ws;  // 1024 floats

  main_kernel<<<B * K + P, BS, 0, stream>>>(x, mu_pop, L_pop, mu_subj, L_subj,
                                            gamma, sid, part, B, T, K, P);
  finalize_kernel<<<1, 256, 0, stream>>>(part, sid, nsub, (float*)d_out, B, K, P,
                                         (float)(B * T));
}